// Round 15
// baseline (138.611 us; speedup 1.0000x reference)
//
#include <hip/hip_runtime.h>
#include <hip/hip_bf16.h>

#define B_   4
#define C_   256
#define CO_  256
#define H_   64
#define W_   64
#define HW_  4096

typedef __attribute__((ext_vector_type(8))) short short8;
typedef __attribute__((ext_vector_type(4))) float f32x4;
typedef __attribute__((ext_vector_type(2))) float f32x2;

static __device__ __forceinline__ unsigned short f2bf(float f) {
    unsigned u = __builtin_bit_cast(unsigned, f);
    unsigned r = (u + 0x7fffu + ((u >> 16) & 1u)) >> 16;
    return (unsigned short)r;
}
static __device__ __forceinline__ f32x2 pk_mul(f32x2 a, f32x2 b) {
    f32x2 d; asm("v_pk_mul_f32 %0, %1, %2" : "=v"(d) : "v"(a), "v"(b)); return d;
}
static __device__ __forceinline__ f32x2 pk_fma(f32x2 a, f32x2 b, f32x2 c) {
    f32x2 d; asm("v_pk_fma_f32 %0, %1, %2, %3" : "=v"(d) : "v"(a), "v"(b), "v"(c)); return d;
}
static __device__ __forceinline__ f32x2 pk_add(f32x2 a, f32x2 b) {
    f32x2 d; asm("v_pk_add_f32 %0, %1, %2" : "=v"(d) : "v"(a), "v"(b)); return d;
}
static __device__ __forceinline__ unsigned cvtpk(float a, float b) {
    unsigned r; asm("v_cvt_pk_bf16_f32 %0, %1, %2" : "=v"(r) : "v"(a), "v"(b)); return r;
}
static __device__ __forceinline__ f32x2 unpack_bf2(unsigned d) {
    f32x2 v;
    v.x = __builtin_bit_cast(float, d << 16);
    v.y = __builtin_bit_cast(float, d & 0xffff0000u);
    return v;
}

// ---------------- K1: fused {NCHW->NHWC bf16 transpose} + {packB} + {dwcT} -----------
__global__ void k_pre(const float* __restrict__ x, unsigned short* __restrict__ xT,
                      const float* __restrict__ w, unsigned short* __restrict__ Bt,
                      const float* __restrict__ dwc_w, float* __restrict__ dwcT)
{
    int bid = blockIdx.x;
    int tid = threadIdx.x;
    if (bid < 1024) {
        __shared__ float t[32][132];
        int b   = bid >> 8;
        int rem = bid & 255;
        int hwT = rem >> 1, cT = rem & 1;
        int hw0 = hwT * 32, c0 = cT * 128;
        const float* src = x + (size_t)b * C_ * HW_;
        {
            int hw4 = (tid & 7) << 2;
            int cr  = tid >> 3;
#pragma unroll
            for (int it = 0; it < 4; ++it) {
                int c = cr + it * 32;
                f32x4 v = *(const f32x4*)(src + (size_t)(c0 + c) * HW_ + hw0 + hw4);
                t[hw4 + 0][c] = v.x;
                t[hw4 + 1][c] = v.y;
                t[hw4 + 2][c] = v.z;
                t[hw4 + 3][c] = v.w;
            }
        }
        __syncthreads();
        {
            int c8  = (tid & 15) << 3;
            int hwr = tid >> 4;
            unsigned short* dst = xT + (size_t)(((b << 12) + hw0) * 256) + c0 + c8;
#pragma unroll
            for (int it = 0; it < 2; ++it) {
                int hw = hwr + it * 16;
                f32x4 va = *(const f32x4*)&t[hw][c8];
                f32x4 vb = *(const f32x4*)&t[hw][c8 + 4];
                uint4 u;
                u.x = cvtpk(va.x, va.y);
                u.y = cvtpk(va.z, va.w);
                u.z = cvtpk(vb.x, vb.y);
                u.w = cvtpk(vb.z, vb.w);
                *(uint4*)(dst + (size_t)hw * 256) = u;
            }
        }
    } else {
        int pb = bid - 1024;                   // 0..2303
        if (pb < 9) dwcT[pb * 256 + tid] = dwc_w[tid * 9 + pb];
        int e = pb * 256 + tid;
        int j   = e & 7;
        int l4  = (e >> 3) & 3;
        int l15 = (e >> 5) & 15;
        int ks  = (e >> 9) & 7;
        int og  = (e >> 12) & 15;
        int k   = e >> 16;
        int o = og * 16 + l15;
        int c = ks * 32 + l4 * 8 + j;
        Bt[e] = f2bf(w[(o * C_ + c) * 9 + k]);
    }
}

// ---------------- K2: offsets — 512 blocks x 512 thr, 16 lanes/position, no LDS ------
__global__ void k_offsets(const unsigned short* __restrict__ xT,
                          const float* __restrict__ dwcT,
                          const float* __restrict__ ln_w,
                          const float* __restrict__ ln_b,
                          const float* __restrict__ fcd_w,
                          const float* __restrict__ fca_w,
                          float* __restrict__ OX, float* __restrict__ OY)
{
    int tid = threadIdx.x;
    int bi = blockIdx.x;
    int g = ((bi & 7) << 6) | (bi >> 3);   // XCD swizzle
    int p0 = g << 5;
    int b = p0 >> 12;
    int y = (p0 >> 6) & 63;
    int xh = p0 & 63;
    int gpos = tid >> 4;                   // 0..31
    int csub = tid & 15;
    int ch0 = csub << 4;
    const unsigned short* xb = xT + (size_t)b * HW_ * C_;

    f32x2 acc2[8];
#pragma unroll
    for (int i = 0; i < 8; ++i) { acc2[i].x = 0.f; acc2[i].y = 0.f; }
#pragma unroll
    for (int j = 0; j < 9; ++j) {
        int gy = y + j / 3 - 1, gx = xh + gpos + j % 3 - 1;
        if (gy >= 0 && gy < H_ && gx >= 0 && gx < W_) {
            const unsigned short* p = xb + (size_t)((gy << 6) + gx) * 256 + ch0;
            short8 rlo = *(const short8*)(p);
            short8 rhi = *(const short8*)(p + 8);
            const float* wrow = dwcT + j * 256 + ch0;
#pragma unroll
            for (int q = 0; q < 4; ++q) {
                f32x4 wv = *(const f32x4*)(wrow + q * 4);
                f32x2 w01v; w01v.x = wv.x; w01v.y = wv.y;
                f32x2 w23v; w23v.x = wv.z; w23v.y = wv.w;
                unsigned lo = (q < 2) ? ((unsigned*)&rlo)[q * 2] : ((unsigned*)&rhi)[(q - 2) * 2];
                unsigned hi = (q < 2) ? ((unsigned*)&rlo)[q * 2 + 1] : ((unsigned*)&rhi)[(q - 2) * 2 + 1];
                acc2[q * 2 + 0] = pk_fma(unpack_bf2(lo), w01v, acc2[q * 2 + 0]);
                acc2[q * 2 + 1] = pk_fma(unpack_bf2(hi), w23v, acc2[q * 2 + 1]);
            }
        }
    }
    f32x2 sum2, sq2;
    sum2.x = 0.f; sum2.y = 0.f; sq2.x = 0.f; sq2.y = 0.f;
#pragma unroll
    for (int i = 0; i < 8; ++i) {
        sum2 = pk_add(sum2, acc2[i]);
        sq2  = pk_fma(acc2[i], acc2[i], sq2);
    }
    float s1 = sum2.x + sum2.y, s2 = sq2.x + sq2.y;
#pragma unroll
    for (int m = 1; m <= 8; m <<= 1) {
        s1 += __shfl_xor(s1, m);
        s2 += __shfl_xor(s2, m);
    }
    float mu  = s1 * (1.f / 256.f);
    float var = s2 * (1.f / 256.f) - mu * mu;
    float rs  = rsqrtf(var + 1e-5f);
    float d1 = 0.f, d2 = 0.f;
#pragma unroll
    for (int q = 0; q < 4; ++q) {
        f32x4 lwv = *(const f32x4*)(ln_w  + ch0 + q * 4);
        f32x4 lbv = *(const f32x4*)(ln_b  + ch0 + q * 4);
        f32x4 fdv = *(const f32x4*)(fcd_w + ch0 + q * 4);
        f32x4 fav = *(const f32x4*)(fca_w + ch0 + q * 4);
#pragma unroll
        for (int i = 0; i < 4; ++i) {
            float av = (i & 1) ? acc2[q * 2 + (i >> 1)].y : acc2[q * 2 + (i >> 1)].x;
            float hn = (av - mu) * rs * lwv[i] + lbv[i];
            hn = fmaxf(hn, 0.f);
            d1 = fmaf(hn, fdv[i], d1);
            d2 = fmaf(hn, fav[i], d2);
        }
    }
#pragma unroll
    for (int m = 1; m <= 8; m <<= 1) {
        d1 += __shfl_xor(d1, m);
        d2 += __shfl_xor(d2, m);
    }
    if (csub == 0) {
        float r0 = fmaxf(d1, 0.f);
        float theta = d2 / (1.f + fabsf(d2)) * 0.017453292519943295f;
        int pos = p0 + gpos;
        OX[pos] = r0 * cosf(theta);
        OY[pos] = r0 * sinf(theta);
    }
}

// ---------------- K3: producer/consumer implicit GEMM deformable conv ----------------
// 512 blocks x 512 threads. Block = 64 pos x 128 outs (N half).
// Waves 0-3 produce (gather+lerp -> LDS); waves 4-7 consume (ds_read+MFMA).
// Consumer wave = 64 pos (4 mf) x 32 outs (2 nf): B reuse 1:4, a-frag reuse x2.
// LDS: 2 x 32KB full-tap buffers... (64 pos x 512B = 32KB each) -> dbuf 64KB.
__launch_bounds__(512, 4)
__global__ void k_main(const unsigned short* __restrict__ xT,
                       const float* __restrict__ OX, const float* __restrict__ OY,
                       const unsigned short* __restrict__ Bt,
                       const float* __restrict__ bias,
                       float* __restrict__ out)
{
    __shared__ __align__(16) unsigned char smem[65536];   // 2 x 32KB tap buffers

    int tid = threadIdx.x;
    int bi = blockIdx.x;
    int g = ((bi & 7) << 6) | (bi >> 3);   // XCD-chunked; pair = same (b,y) row
    int tile = g >> 1;                     // 0..255 : (b, y) row
    int n0g = g & 1;                       // N half
    int b = tile >> 6;
    int y = tile & 63;

    int lane = tid & 63, wid = tid >> 6;
    int l15 = lane & 15, l4 = lane >> 4;
    bool producer = (wid < 4);

    // ---------------- producer state ----------------
    int gpos = tid >> 2;                   // 0..63 position (256 producer threads, 4/pos)
    unsigned qc = (unsigned)tid & 3u;      // 128B quarter
    const char* xbB = (const char*)(xT + (size_t)b * HW_ * C_);
    float ox = 0.f, oy = 0.f;
    if (producer) { ox = OX[(tile << 6) + gpos]; oy = OY[(tile << 6) + gpos]; }
    unsigned pwbase = (unsigned)gpos * 512u + qc * 128u;
    unsigned pswz = ((unsigned)gpos & 7u);

    unsigned o00, o01, o10, o11;
    f32x2 W00, W01, W10, W11;

#define GADDR(k)                                                                  \
    {   int ky = (k) / 3, kx = (k) - ky * 3;                                      \
        float dyv = ((k) <= 4) ? ox : oy;                                         \
        float dxv = ((k) <= 3) ? ox : oy;                                         \
        float py = (float)(y - 1 + ky) + dyv;                                     \
        float px = (float)(gpos - 1 + kx) + dxv;                                  \
        float y0f = floorf(py), x0f = floorf(px);                                 \
        int y0 = (int)y0f, x0 = (int)x0f;                                         \
        int y1 = y0 + 1, x1 = x0 + 1;                                             \
        float wy1 = py - y0f, wy0 = 1.f - wy1;                                    \
        float wx1 = px - x0f, wx0 = 1.f - wx1;                                    \
        float vy0 = (y0 >= 0 && y0 < H_) ? 1.f : 0.f;                             \
        float vy1 = (y1 >= 0 && y1 < H_) ? 1.f : 0.f;                             \
        float vx0 = (x0 >= 0 && x0 < W_) ? 1.f : 0.f;                             \
        float vx1 = (x1 >= 0 && x1 < W_) ? 1.f : 0.f;                             \
        float w00 = wy0 * wx0 * vy0 * vx0, w01 = wy0 * wx1 * vy0 * vx1;           \
        float w10 = wy1 * wx0 * vy1 * vx0, w11 = wy1 * wx1 * vy1 * vx1;           \
        W00.x = w00; W00.y = w00; W01.x = w01; W01.y = w01;                       \
        W10.x = w10; W10.y = w10; W11.x = w11; W11.y = w11;                       \
        int y0c = min(max(y0, 0), H_ - 1), y1c = min(max(y1, 0), H_ - 1);         \
        int x0c = min(max(x0, 0), W_ - 1), x1c = min(max(x1, 0), W_ - 1);         \
        o00 = (unsigned)((y0c << 6) + x0c) * 512u + qc * 128u;                    \
        o01 = (unsigned)((y0c << 6) + x1c) * 512u + qc * 128u;                    \
        o10 = (unsigned)((y1c << 6) + x0c) * 512u + qc * 128u;                    \
        o11 = (unsigned)((y1c << 6) + x1c) * 512u + qc * 128u;                    \
    }

    // produce this thread's 128B quarter of its position into buffer hbase
#define GATHER_TAP(hbase)                                                         \
    {   _Pragma("unroll")                                                         \
        for (int j = 0; j < 8; ++j) {                                             \
            unsigned gb = (unsigned)j * 16u;                                      \
            short8 r00 = *(const short8*)(xbB + o00 + gb);                        \
            short8 r01 = *(const short8*)(xbB + o01 + gb);                        \
            short8 r10 = *(const short8*)(xbB + o10 + gb);                        \
            short8 r11 = *(const short8*)(xbB + o11 + gb);                        \
            uint4 pkv;                                                            \
            _Pragma("unroll")                                                     \
            for (int dw = 0; dw < 4; ++dw) {                                      \
                f32x2 a2 = pk_mul(unpack_bf2(((unsigned*)&r00)[dw]), W00);        \
                a2 = pk_fma(unpack_bf2(((unsigned*)&r01)[dw]), W01, a2);          \
                a2 = pk_fma(unpack_bf2(((unsigned*)&r10)[dw]), W10, a2);          \
                a2 = pk_fma(unpack_bf2(((unsigned*)&r11)[dw]), W11, a2);          \
                ((unsigned*)&pkv)[dw] = cvtpk(a2.x, a2.y);                        \
            }                                                                     \
            *(uint4*)(smem + (hbase) + pwbase + (((unsigned)j ^ pswz) * 16u)) = pkv; \
        }                                                                         \
    }

    // ---------------- consumer state ----------------
    int cwid = wid - 4;                    // 0..3
    f32x4 acc[4][2];
#pragma unroll
    for (int m = 0; m < 4; ++m)
#pragma unroll
        for (int n = 0; n < 2; ++n) {
            acc[m][n].x = 0.f; acc[m][n].y = 0.f; acc[m][n].z = 0.f; acc[m][n].w = 0.f;
        }
    const unsigned short* bwave = Bt + (unsigned)(n0g * 8 + (cwid < 0 ? 0 : cwid) * 2) * 4096u
                                     + (unsigned)(l15 * 32 + l4 * 8);

    // MFMA over tap k from buffer hbase: 8 ks x (4 mf x 2 nf)
#define MFMA_TAP(k, hbase)                                                        \
    {   const unsigned short* bk = bwave + (unsigned)(k) * 65536u;                \
        _Pragma("unroll")                                                         \
        for (int ks = 0; ks < 8; ++ks) {                                          \
            short8 bf0 = *(const short8*)(bk + ks * 512);                         \
            short8 bf1 = *(const short8*)(bk + 4096 + ks * 512);                  \
            unsigned sl = ((unsigned)(ks >> 1)) * 128u +                          \
                          ((((unsigned)(ks & 1) * 4u + (unsigned)l4) ^           \
                            ((unsigned)l15 & 7u)) * 16u);                         \
            _Pragma("unroll")                                                     \
            for (int mf = 0; mf < 4; ++mf) {                                      \
                unsigned row = (unsigned)(mf * 16 + l15);                         \
                short8 a = *(const short8*)(smem + (hbase) + row * 512u + sl);    \
                acc[mf][0] = __builtin_amdgcn_mfma_f32_16x16x32_bf16(a, bf0, acc[mf][0], 0, 0, 0); \
                acc[mf][1] = __builtin_amdgcn_mfma_f32_16x16x32_bf16(a, bf1, acc[mf][1], 0, 0, 0); \
            }                                                                     \
        }                                                                         \
    }

    // ---- prologue: producers fill tap 0 into buf0 ----
    if (producer) {
        GADDR(0);
        GATHER_TAP(0u);
    }
    __syncthreads();

#pragma unroll
    for (int k = 0; k < 9; ++k) {
        unsigned cur = (k & 1) ? 32768u : 0u;
        unsigned nxt = (k & 1) ? 0u : 32768u;
        if (producer) {
            if (k < 8) {
                GADDR(k + 1);
                GATHER_TAP(nxt);
            }
        } else {
            MFMA_TAP(k, cur);
        }
        __syncthreads();
    }

    // ---- epilogue: consumers store directly ----
    if (!producer) {
#pragma unroll
        for (int nf = 0; nf < 2; ++nf) {
            int col = n0g * 128 + cwid * 32 + nf * 16 + l15;
            float bv = bias[col];
            float* obase = out + ((size_t)(b * CO_ + col)) * HW_ + (y << 6);
#pragma unroll
            for (int mf = 0; mf < 4; ++mf) {
                f32x4 v;
                v.x = acc[mf][nf].x + bv;
                v.y = acc[mf][nf].y + bv;
                v.z = acc[mf][nf].z + bv;
                v.w = acc[mf][nf].w + bv;
                *(f32x4*)(obase + mf * 16 + l4 * 4) = v;
            }
        }
    }
}

extern "C" void kernel_launch(void* const* d_in, const int* in_sizes, int n_in,
                              void* d_out, int out_size, void* d_ws, size_t ws_size,
                              hipStream_t stream) {
    const float* x      = (const float*)d_in[0];
    const float* dwc_w  = (const float*)d_in[1];
    const float* ln_w   = (const float*)d_in[2];
    const float* ln_b   = (const float*)d_in[3];
    const float* fcd_w  = (const float*)d_in[4];
    const float* fca_w  = (const float*)d_in[5];
    const float* dconv_w= (const float*)d_in[6];
    const float* dconv_b= (const float*)d_in[7];
    float* out = (float*)d_out;

    unsigned char* ws = (unsigned char*)d_ws;
    unsigned short* xT = (unsigned short*)(ws);                 // 8 MB bf16 NHWC
    unsigned short* Bt = (unsigned short*)(ws + 8388608);       // 1.18 MB
    float* dwcT        = (float*)(ws + 9568256);                // 9 KB
    float* OX          = (float*)(ws + 9577472);                // 64 KB
    float* OY          = (float*)(ws + 9643008);                // 64 KB

    k_pre<<<3328, 256, 0, stream>>>(x, xT, dconv_w, Bt, dwc_w, dwcT);
    k_offsets<<<512, 512, 0, stream>>>(xT, dwcT, ln_w, ln_b, fcd_w, fca_w, OX, OY);
    k_main<<<512, 512, 0, stream>>>(xT, OX, OY, Bt, dconv_b, out);
}

// Round 16
// 76.402 us; speedup vs baseline: 1.8142x; 1.8142x over previous
//
#include <hip/hip_runtime.h>
#include <hip/hip_bf16.h>

#define B_   4
#define C_   256
#define CO_  256
#define H_   64
#define W_   64
#define HW_  4096

typedef __attribute__((ext_vector_type(8))) short short8;
typedef __attribute__((ext_vector_type(4))) float f32x4;
typedef __attribute__((ext_vector_type(2))) float f32x2;

static __device__ __forceinline__ unsigned short f2bf(float f) {
    unsigned u = __builtin_bit_cast(unsigned, f);
    unsigned r = (u + 0x7fffu + ((u >> 16) & 1u)) >> 16;
    return (unsigned short)r;
}
static __device__ __forceinline__ f32x2 pk_mul(f32x2 a, f32x2 b) {
    f32x2 d; asm("v_pk_mul_f32 %0, %1, %2" : "=v"(d) : "v"(a), "v"(b)); return d;
}
static __device__ __forceinline__ f32x2 pk_fma(f32x2 a, f32x2 b, f32x2 c) {
    f32x2 d; asm("v_pk_fma_f32 %0, %1, %2, %3" : "=v"(d) : "v"(a), "v"(b), "v"(c)); return d;
}
static __device__ __forceinline__ f32x2 pk_add(f32x2 a, f32x2 b) {
    f32x2 d; asm("v_pk_add_f32 %0, %1, %2" : "=v"(d) : "v"(a), "v"(b)); return d;
}
static __device__ __forceinline__ unsigned cvtpk(float a, float b) {
    unsigned r; asm("v_cvt_pk_bf16_f32 %0, %1, %2" : "=v"(r) : "v"(a), "v"(b)); return r;
}
static __device__ __forceinline__ f32x2 unpack_bf2(unsigned d) {
    f32x2 v;
    v.x = __builtin_bit_cast(float, d << 16);
    v.y = __builtin_bit_cast(float, d & 0xffff0000u);
    return v;
}

// ---------------- K1: fused {NCHW->NHWC bf16 transpose} + {packB} + {dwcT} -----------
__global__ void k_pre(const float* __restrict__ x, unsigned short* __restrict__ xT,
                      const float* __restrict__ w, unsigned short* __restrict__ Bt,
                      const float* __restrict__ dwc_w, float* __restrict__ dwcT)
{
    int bid = blockIdx.x;
    int tid = threadIdx.x;
    if (bid < 1024) {
        __shared__ float t[32][132];
        int b   = bid >> 8;
        int rem = bid & 255;
        int hwT = rem >> 1, cT = rem & 1;
        int hw0 = hwT * 32, c0 = cT * 128;
        const float* src = x + (size_t)b * C_ * HW_;
        {
            int hw4 = (tid & 7) << 2;
            int cr  = tid >> 3;
#pragma unroll
            for (int it = 0; it < 4; ++it) {
                int c = cr + it * 32;
                f32x4 v = *(const f32x4*)(src + (size_t)(c0 + c) * HW_ + hw0 + hw4);
                t[hw4 + 0][c] = v.x;
                t[hw4 + 1][c] = v.y;
                t[hw4 + 2][c] = v.z;
                t[hw4 + 3][c] = v.w;
            }
        }
        __syncthreads();
        {
            int c8  = (tid & 15) << 3;
            int hwr = tid >> 4;
            unsigned short* dst = xT + (size_t)(((b << 12) + hw0) * 256) + c0 + c8;
#pragma unroll
            for (int it = 0; it < 2; ++it) {
                int hw = hwr + it * 16;
                f32x4 va = *(const f32x4*)&t[hw][c8];
                f32x4 vb = *(const f32x4*)&t[hw][c8 + 4];
                uint4 u;
                u.x = cvtpk(va.x, va.y);
                u.y = cvtpk(va.z, va.w);
                u.z = cvtpk(vb.x, vb.y);
                u.w = cvtpk(vb.z, vb.w);
                *(uint4*)(dst + (size_t)hw * 256) = u;
            }
        }
    } else {
        int pb = bid - 1024;                   // 0..2303
        if (pb < 9) dwcT[pb * 256 + tid] = dwc_w[tid * 9 + pb];
        int e = pb * 256 + tid;
        int j   = e & 7;
        int l4  = (e >> 3) & 3;
        int l15 = (e >> 5) & 15;
        int ks  = (e >> 9) & 7;
        int og  = (e >> 12) & 15;
        int k   = e >> 16;
        int o = og * 16 + l15;
        int c = ks * 32 + l4 * 8 + j;
        Bt[e] = f2bf(w[(o * C_ + c) * 9 + k]);
    }
}

// ---------------- K2: offsets — 512 blocks x 512 thr, 16 lanes/position, no LDS ------
__global__ void k_offsets(const unsigned short* __restrict__ xT,
                          const float* __restrict__ dwcT,
                          const float* __restrict__ ln_w,
                          const float* __restrict__ ln_b,
                          const float* __restrict__ fcd_w,
                          const float* __restrict__ fca_w,
                          float* __restrict__ OX, float* __restrict__ OY)
{
    int tid = threadIdx.x;
    int bi = blockIdx.x;
    int g = ((bi & 7) << 6) | (bi >> 3);   // XCD swizzle
    int p0 = g << 5;
    int b = p0 >> 12;
    int y = (p0 >> 6) & 63;
    int xh = p0 & 63;
    int gpos = tid >> 4;                   // 0..31
    int csub = tid & 15;
    int ch0 = csub << 4;
    const unsigned short* xb = xT + (size_t)b * HW_ * C_;

    f32x2 acc2[8];
#pragma unroll
    for (int i = 0; i < 8; ++i) { acc2[i].x = 0.f; acc2[i].y = 0.f; }
#pragma unroll
    for (int j = 0; j < 9; ++j) {
        int gy = y + j / 3 - 1, gx = xh + gpos + j % 3 - 1;
        if (gy >= 0 && gy < H_ && gx >= 0 && gx < W_) {
            const unsigned short* p = xb + (size_t)((gy << 6) + gx) * 256 + ch0;
            short8 rlo = *(const short8*)(p);
            short8 rhi = *(const short8*)(p + 8);
            const float* wrow = dwcT + j * 256 + ch0;
#pragma unroll
            for (int q = 0; q < 4; ++q) {
                f32x4 wv = *(const f32x4*)(wrow + q * 4);
                f32x2 w01v; w01v.x = wv.x; w01v.y = wv.y;
                f32x2 w23v; w23v.x = wv.z; w23v.y = wv.w;
                unsigned lo = (q < 2) ? ((unsigned*)&rlo)[q * 2] : ((unsigned*)&rhi)[(q - 2) * 2];
                unsigned hi = (q < 2) ? ((unsigned*)&rlo)[q * 2 + 1] : ((unsigned*)&rhi)[(q - 2) * 2 + 1];
                acc2[q * 2 + 0] = pk_fma(unpack_bf2(lo), w01v, acc2[q * 2 + 0]);
                acc2[q * 2 + 1] = pk_fma(unpack_bf2(hi), w23v, acc2[q * 2 + 1]);
            }
        }
    }
    f32x2 sum2, sq2;
    sum2.x = 0.f; sum2.y = 0.f; sq2.x = 0.f; sq2.y = 0.f;
#pragma unroll
    for (int i = 0; i < 8; ++i) {
        sum2 = pk_add(sum2, acc2[i]);
        sq2  = pk_fma(acc2[i], acc2[i], sq2);
    }
    float s1 = sum2.x + sum2.y, s2 = sq2.x + sq2.y;
#pragma unroll
    for (int m = 1; m <= 8; m <<= 1) {
        s1 += __shfl_xor(s1, m);
        s2 += __shfl_xor(s2, m);
    }
    float mu  = s1 * (1.f / 256.f);
    float var = s2 * (1.f / 256.f) - mu * mu;
    float rs  = rsqrtf(var + 1e-5f);
    float d1 = 0.f, d2 = 0.f;
#pragma unroll
    for (int q = 0; q < 4; ++q) {
        f32x4 lwv = *(const f32x4*)(ln_w  + ch0 + q * 4);
        f32x4 lbv = *(const f32x4*)(ln_b  + ch0 + q * 4);
        f32x4 fdv = *(const f32x4*)(fcd_w + ch0 + q * 4);
        f32x4 fav = *(const f32x4*)(fca_w + ch0 + q * 4);
#pragma unroll
        for (int i = 0; i < 4; ++i) {
            float av = (i & 1) ? acc2[q * 2 + (i >> 1)].y : acc2[q * 2 + (i >> 1)].x;
            float hn = (av - mu) * rs * lwv[i] + lbv[i];
            hn = fmaxf(hn, 0.f);
            d1 = fmaf(hn, fdv[i], d1);
            d2 = fmaf(hn, fav[i], d2);
        }
    }
#pragma unroll
    for (int m = 1; m <= 8; m <<= 1) {
        d1 += __shfl_xor(d1, m);
        d2 += __shfl_xor(d2, m);
    }
    if (csub == 0) {
        float r0 = fmaxf(d1, 0.f);
        float theta = d2 / (1.f + fabsf(d2)) * 0.017453292519943295f;
        int pos = p0 + gpos;
        OX[pos] = r0 * cosf(theta);
        OY[pos] = r0 * sinf(theta);
    }
}

// ---------------- K3: implicit GEMM deformable conv, half-tap dbuf + B reg-prefetch --
// 512 blocks x 512 threads. Block = full row (64 pos) x 128 outs (N half).
// B prefetched one PHASE ahead via pinned asm loads; the inter-phase __syncthreads'
// implicit vmcnt(0) is the fence (no hand vmcnt needed; live range is one phase).
__launch_bounds__(512, 4)
__global__ void k_main(const unsigned short* __restrict__ xT,
                       const float* __restrict__ OX, const float* __restrict__ OY,
                       const unsigned short* __restrict__ Bt,
                       const float* __restrict__ bias,
                       float* __restrict__ out)
{
    __shared__ __align__(16) unsigned char smem[32768];   // 2 x 16KB half-tap buffers

    int tid = threadIdx.x;
    int bi = blockIdx.x;
    int g = ((bi & 7) << 6) | (bi >> 3);   // XCD-chunked; pair = same (b,y) row
    int tile = g >> 1;                     // 0..255 : (b, y) row
    int n0g = g & 1;                       // N half
    int b = tile >> 6;
    int y = tile & 63;

    int lane = tid & 63, wid = tid >> 6;
    int l15 = lane & 15, l4 = lane >> 4;

    f32x4 acc[4];
#pragma unroll
    for (int m = 0; m < 4; ++m) {
        acc[m].x = 0.f; acc[m].y = 0.f; acc[m].z = 0.f; acc[m].w = 0.f;
    }

    int gpos = tid >> 3;                   // 0..63 : position (x coordinate)
    unsigned csub = (unsigned)tid & 7u;
    const char* xbB = (const char*)(xT + (size_t)b * HW_ * C_);
    const unsigned short* bwave = Bt + (unsigned)(n0g * 8 + wid) * 4096u
                                     + (unsigned)(l15 * 32 + l4 * 8);
    unsigned rowb = (unsigned)gpos * 256u;
    unsigned wsl0 = (csub ^ ((unsigned)gpos & 15u)) << 4;
    unsigned wsl1 = ((8u + csub) ^ ((unsigned)gpos & 15u)) << 4;
    float ox = OX[(tile << 6) + gpos], oy = OY[(tile << 6) + gpos];

    // persistent per-tap gather state
    unsigned o00, o01, o10, o11;
    f32x2 W00, W01, W10, W11;

#define GADDR(k)                                                                  \
    {   int ky = (k) / 3, kx = (k) - ky * 3;                                      \
        float dyv = ((k) <= 4) ? ox : oy;                                         \
        float dxv = ((k) <= 3) ? ox : oy;                                         \
        float py = (float)(y - 1 + ky) + dyv;                                     \
        float px = (float)(gpos - 1 + kx) + dxv;                                  \
        float y0f = floorf(py), x0f = floorf(px);                                 \
        int y0 = (int)y0f, x0 = (int)x0f;                                         \
        int y1 = y0 + 1, x1 = x0 + 1;                                             \
        float wy1 = py - y0f, wy0 = 1.f - wy1;                                    \
        float wx1 = px - x0f, wx0 = 1.f - wx1;                                    \
        float vy0 = (y0 >= 0 && y0 < H_) ? 1.f : 0.f;                             \
        float vy1 = (y1 >= 0 && y1 < H_) ? 1.f : 0.f;                             \
        float vx0 = (x0 >= 0 && x0 < W_) ? 1.f : 0.f;                             \
        float vx1 = (x1 >= 0 && x1 < W_) ? 1.f : 0.f;                             \
        float w00 = wy0 * wx0 * vy0 * vx0, w01 = wy0 * wx1 * vy0 * vx1;           \
        float w10 = wy1 * wx0 * vy1 * vx0, w11 = wy1 * wx1 * vy1 * vx1;           \
        W00.x = w00; W00.y = w00; W01.x = w01; W01.y = w01;                       \
        W10.x = w10; W10.y = w10; W11.x = w11; W11.y = w11;                       \
        int y0c = min(max(y0, 0), H_ - 1), y1c = min(max(y1, 0), H_ - 1);         \
        int x0c = min(max(x0, 0), W_ - 1), x1c = min(max(x1, 0), W_ - 1);         \
        unsigned cb = csub << 4;                                                  \
        o00 = (unsigned)((y0c << 6) + x0c) * 512u + cb;                           \
        o01 = (unsigned)((y0c << 6) + x1c) * 512u + cb;                           \
        o10 = (unsigned)((y1c << 6) + x0c) * 512u + cb;                           \
        o11 = (unsigned)((y1c << 6) + x1c) * 512u + cb;                           \
    }

#define GATHER_HALF(h, hbase)                                                     \
    {   _Pragma("unroll")                                                         \
        for (int cq2 = 0; cq2 < 2; ++cq2) {                                       \
            unsigned gb = (unsigned)(h) * 256u + (unsigned)cq2 * 128u;            \
            short8 r00 = *(const short8*)(xbB + o00 + gb);                        \
            short8 r01 = *(const short8*)(xbB + o01 + gb);                        \
            short8 r10 = *(const short8*)(xbB + o10 + gb);                        \
            short8 r11 = *(const short8*)(xbB + o11 + gb);                        \
            uint4 pkv;                                                            \
            _Pragma("unroll")                                                     \
            for (int dw = 0; dw < 4; ++dw) {                                      \
                f32x2 a2 = pk_mul(unpack_bf2(((unsigned*)&r00)[dw]), W00);        \
                a2 = pk_fma(unpack_bf2(((unsigned*)&r01)[dw]), W01, a2);          \
                a2 = pk_fma(unpack_bf2(((unsigned*)&r10)[dw]), W10, a2);          \
                a2 = pk_fma(unpack_bf2(((unsigned*)&r11)[dw]), W11, a2);          \
                ((unsigned*)&pkv)[dw] = cvtpk(a2.x, a2.y);                        \
            }                                                                     \
            *(uint4*)(smem + (hbase) + rowb + (cq2 ? wsl1 : wsl0)) = pkv;         \
        }                                                                         \
    }

    // pinned B half-tap prefetch: 4 x 1KB-coalesced loads into registers.
    // Validity fence = the __syncthreads() (compiler emits vmcnt(0) before barrier).
#define ISSUE_B(D, kk, h)                                                         \
    {   const unsigned short* _b = bwave + (unsigned)(kk) * 65536u + (unsigned)(h) * 2048u; \
        asm volatile("global_load_dwordx4 %0, %1, off"             : "=v"(D[0]) : "v"(_b)); \
        asm volatile("global_load_dwordx4 %0, %1, off offset:1024" : "=v"(D[1]) : "v"(_b)); \
        asm volatile("global_load_dwordx4 %0, %1, off offset:2048" : "=v"(D[2]) : "v"(_b)); \
        asm volatile("global_load_dwordx4 %0, %1, off offset:3072" : "=v"(D[3]) : "v"(_b)); \
        __builtin_amdgcn_sched_barrier(0);                                        \
    }

    // MFMA on half h of tap k from buffer hbase, B from prefetched regs D[0..3]
#define MFMA_HALF_R(D, h, hbase)                                                  \
    {   __builtin_amdgcn_s_setprio(1);                                            \
        _Pragma("unroll")                                                         \
        for (int ks2 = 0; ks2 < 4; ++ks2) {                                       \
            int ks = (h) * 4 + ks2;                                               \
            unsigned sl = ((unsigned)(ks2 * 4 + l4) ^ (unsigned)l15) << 4;        \
            _Pragma("unroll")                                                     \
            for (int mf = 0; mf < 4; ++mf) {                                      \
                unsigned row = (unsigned)(mf * 16 + l15);                         \
                short8 a = *(const short8*)(smem + (hbase) + row * 256u + sl);    \
                acc[mf] = __builtin_amdgcn_mfma_f32_16x16x32_bf16(a, D[ks2], acc[mf], 0, 0, 0); \
            }                                                                     \
        }                                                                         \
        __builtin_amdgcn_s_setprio(0);                                            \
    }

    short8 BP[4], BQ[4];

    // ---- prologue: issue B(0,h0); gather tap 0 half 0 into buf0 ----
    GADDR(0);
    ISSUE_B(BP, 0, 0);
    GATHER_HALF(0, 0u);
    __syncthreads();                       // fences BP

#pragma unroll
    for (int k = 0; k < 9; ++k) {
        // phase A: issue B(k,h1); gather(k,h1->buf1) || MFMA(k,h0) from BP+buf0
        ISSUE_B(BQ, k, 1);
        GATHER_HALF(1, 16384u);
        MFMA_HALF_R(BP, 0, 0u);
        __syncthreads();                   // fences BQ
        // phase B: issue B(k+1,h0); gather(k+1,h0->buf0) || MFMA(k,h1) from BQ+buf1
        if (k < 8) {
            ISSUE_B(BP, k + 1, 0);
            GADDR(k + 1);
            GATHER_HALF(0, 0u);
        }
        MFMA_HALF_R(BQ, 1, 16384u);
        __syncthreads();                   // fences BP
    }

    // ---- epilogue: direct global stores ----
    int col = n0g * 128 + wid * 16 + l15;
    float bv = bias[col];
    float* obase = out + ((size_t)(b * CO_ + col)) * HW_ + (y << 6);
#pragma unroll
    for (int mf = 0; mf < 4; ++mf) {
        f32x4 v;
        v.x = acc[mf].x + bv;
        v.y = acc[mf].y + bv;
        v.z = acc[mf].z + bv;
        v.w = acc[mf].w + bv;
        *(f32x4*)(obase + mf * 16 + l4 * 4) = v;
    }
}

extern "C" void kernel_launch(void* const* d_in, const int* in_sizes, int n_in,
                              void* d_out, int out_size, void* d_ws, size_t ws_size,
                              hipStream_t stream) {
    const float* x      = (const float*)d_in[0];
    const float* dwc_w  = (const float*)d_in[1];
    const float* ln_w   = (const float*)d_in[2];
    const float* ln_b   = (const float*)d_in[3];
    const float* fcd_w  = (const float*)d_in[4];
    const float* fca_w  = (const float*)d_in[5];
    const float* dconv_w= (const float*)d_in[6];
    const float* dconv_b= (const float*)d_in[7];
    float* out = (float*)d_out;

    unsigned char* ws = (unsigned char*)d_ws;
    unsigned short* xT = (unsigned short*)(ws);                 // 8 MB bf16 NHWC
    unsigned short* Bt = (unsigned short*)(ws + 8388608);       // 1.18 MB
    float* dwcT        = (float*)(ws + 9568256);                // 9 KB
    float* OX          = (float*)(ws + 9577472);                // 64 KB
    float* OY          = (float*)(ws + 9643008);                // 64 KB

    k_pre<<<3328, 256, 0, stream>>>(x, xT, dconv_w, Bt, dwc_w, dwcT);
    k_offsets<<<512, 512, 0, stream>>>(xT, dwcT, ln_w, ln_b, fcd_w, fca_w, OX, OY);
    k_main<<<512, 512, 0, stream>>>(xT, OX, OY, Bt, dconv_b, out);
}

// Round 17
// 68.877 us; speedup vs baseline: 2.0124x; 1.1093x over previous
//
#include <hip/hip_runtime.h>
#include <hip/hip_bf16.h>

#define B_   4
#define C_   256
#define CO_  256
#define H_   64
#define W_   64
#define HW_  4096

typedef __attribute__((ext_vector_type(8))) short short8;
typedef __attribute__((ext_vector_type(4))) float f32x4;
typedef __attribute__((ext_vector_type(2))) float f32x2;

static __device__ __forceinline__ unsigned short f2bf(float f) {
    unsigned u = __builtin_bit_cast(unsigned, f);
    unsigned r = (u + 0x7fffu + ((u >> 16) & 1u)) >> 16;
    return (unsigned short)r;
}
static __device__ __forceinline__ f32x2 pk_mul(f32x2 a, f32x2 b) {
    f32x2 d; asm("v_pk_mul_f32 %0, %1, %2" : "=v"(d) : "v"(a), "v"(b)); return d;
}
static __device__ __forceinline__ f32x2 pk_fma(f32x2 a, f32x2 b, f32x2 c) {
    f32x2 d; asm("v_pk_fma_f32 %0, %1, %2, %3" : "=v"(d) : "v"(a), "v"(b), "v"(c)); return d;
}
static __device__ __forceinline__ f32x2 pk_add(f32x2 a, f32x2 b) {
    f32x2 d; asm("v_pk_add_f32 %0, %1, %2" : "=v"(d) : "v"(a), "v"(b)); return d;
}
static __device__ __forceinline__ unsigned cvtpk(float a, float b) {
    unsigned r; asm("v_cvt_pk_bf16_f32 %0, %1, %2" : "=v"(r) : "v"(a), "v"(b)); return r;
}
static __device__ __forceinline__ f32x2 unpack_bf2(unsigned d) {
    f32x2 v;
    v.x = __builtin_bit_cast(float, d << 16);
    v.y = __builtin_bit_cast(float, d & 0xffff0000u);
    return v;
}

// ---------------- K1: fused {NCHW->NHWC bf16 transpose} + {packB} + {dwcT} -----------
__global__ void k_pre(const float* __restrict__ x, unsigned short* __restrict__ xT,
                      const float* __restrict__ w, unsigned short* __restrict__ Bt,
                      const float* __restrict__ dwc_w, float* __restrict__ dwcT)
{
    int bid = blockIdx.x;
    int tid = threadIdx.x;
    if (bid < 1024) {
        __shared__ float t[32][132];
        int b   = bid >> 8;
        int rem = bid & 255;
        int hwT = rem >> 1, cT = rem & 1;
        int hw0 = hwT * 32, c0 = cT * 128;
        const float* src = x + (size_t)b * C_ * HW_;
        {
            int hw4 = (tid & 7) << 2;
            int cr  = tid >> 3;
#pragma unroll
            for (int it = 0; it < 4; ++it) {
                int c = cr + it * 32;
                f32x4 v = *(const f32x4*)(src + (size_t)(c0 + c) * HW_ + hw0 + hw4);
                t[hw4 + 0][c] = v.x;
                t[hw4 + 1][c] = v.y;
                t[hw4 + 2][c] = v.z;
                t[hw4 + 3][c] = v.w;
            }
        }
        __syncthreads();
        {
            int c8  = (tid & 15) << 3;
            int hwr = tid >> 4;
            unsigned short* dst = xT + (size_t)(((b << 12) + hw0) * 256) + c0 + c8;
#pragma unroll
            for (int it = 0; it < 2; ++it) {
                int hw = hwr + it * 16;
                f32x4 va = *(const f32x4*)&t[hw][c8];
                f32x4 vb = *(const f32x4*)&t[hw][c8 + 4];
                uint4 u;
                u.x = cvtpk(va.x, va.y);
                u.y = cvtpk(va.z, va.w);
                u.z = cvtpk(vb.x, vb.y);
                u.w = cvtpk(vb.z, vb.w);
                *(uint4*)(dst + (size_t)hw * 256) = u;
            }
        }
    } else {
        int pb = bid - 1024;                   // 0..2303
        if (pb < 9) dwcT[pb * 256 + tid] = dwc_w[tid * 9 + pb];
        int e = pb * 256 + tid;
        int j   = e & 7;
        int l4  = (e >> 3) & 3;
        int l15 = (e >> 5) & 15;
        int ks  = (e >> 9) & 7;
        int og  = (e >> 12) & 15;
        int k   = e >> 16;
        int o = og * 16 + l15;
        int c = ks * 32 + l4 * 8 + j;
        Bt[e] = f2bf(w[(o * C_ + c) * 9 + k]);
    }
}

// ---------------- K2: offsets — 512 blocks x 512 thr, 16 lanes/position, no LDS ------
__global__ void k_offsets(const unsigned short* __restrict__ xT,
                          const float* __restrict__ dwcT,
                          const float* __restrict__ ln_w,
                          const float* __restrict__ ln_b,
                          const float* __restrict__ fcd_w,
                          const float* __restrict__ fca_w,
                          float* __restrict__ OX, float* __restrict__ OY)
{
    int tid = threadIdx.x;
    int bi = blockIdx.x;
    int g = ((bi & 7) << 6) | (bi >> 3);   // XCD swizzle
    int p0 = g << 5;
    int b = p0 >> 12;
    int y = (p0 >> 6) & 63;
    int xh = p0 & 63;
    int gpos = tid >> 4;                   // 0..31
    int csub = tid & 15;
    int ch0 = csub << 4;
    const unsigned short* xb = xT + (size_t)b * HW_ * C_;

    f32x2 acc2[8];
#pragma unroll
    for (int i = 0; i < 8; ++i) { acc2[i].x = 0.f; acc2[i].y = 0.f; }
#pragma unroll
    for (int j = 0; j < 9; ++j) {
        int gy = y + j / 3 - 1, gx = xh + gpos + j % 3 - 1;
        if (gy >= 0 && gy < H_ && gx >= 0 && gx < W_) {
            const unsigned short* p = xb + (size_t)((gy << 6) + gx) * 256 + ch0;
            short8 rlo = *(const short8*)(p);
            short8 rhi = *(const short8*)(p + 8);
            const float* wrow = dwcT + j * 256 + ch0;
#pragma unroll
            for (int q = 0; q < 4; ++q) {
                f32x4 wv = *(const f32x4*)(wrow + q * 4);
                f32x2 w01v; w01v.x = wv.x; w01v.y = wv.y;
                f32x2 w23v; w23v.x = wv.z; w23v.y = wv.w;
                unsigned lo = (q < 2) ? ((unsigned*)&rlo)[q * 2] : ((unsigned*)&rhi)[(q - 2) * 2];
                unsigned hi = (q < 2) ? ((unsigned*)&rlo)[q * 2 + 1] : ((unsigned*)&rhi)[(q - 2) * 2 + 1];
                acc2[q * 2 + 0] = pk_fma(unpack_bf2(lo), w01v, acc2[q * 2 + 0]);
                acc2[q * 2 + 1] = pk_fma(unpack_bf2(hi), w23v, acc2[q * 2 + 1]);
            }
        }
    }
    f32x2 sum2, sq2;
    sum2.x = 0.f; sum2.y = 0.f; sq2.x = 0.f; sq2.y = 0.f;
#pragma unroll
    for (int i = 0; i < 8; ++i) {
        sum2 = pk_add(sum2, acc2[i]);
        sq2  = pk_fma(acc2[i], acc2[i], sq2);
    }
    float s1 = sum2.x + sum2.y, s2 = sq2.x + sq2.y;
#pragma unroll
    for (int m = 1; m <= 8; m <<= 1) {
        s1 += __shfl_xor(s1, m);
        s2 += __shfl_xor(s2, m);
    }
    float mu  = s1 * (1.f / 256.f);
    float var = s2 * (1.f / 256.f) - mu * mu;
    float rs  = rsqrtf(var + 1e-5f);
    float d1 = 0.f, d2 = 0.f;
#pragma unroll
    for (int q = 0; q < 4; ++q) {
        f32x4 lwv = *(const f32x4*)(ln_w  + ch0 + q * 4);
        f32x4 lbv = *(const f32x4*)(ln_b  + ch0 + q * 4);
        f32x4 fdv = *(const f32x4*)(fcd_w + ch0 + q * 4);
        f32x4 fav = *(const f32x4*)(fca_w + ch0 + q * 4);
#pragma unroll
        for (int i = 0; i < 4; ++i) {
            float av = (i & 1) ? acc2[q * 2 + (i >> 1)].y : acc2[q * 2 + (i >> 1)].x;
            float hn = (av - mu) * rs * lwv[i] + lbv[i];
            hn = fmaxf(hn, 0.f);
            d1 = fmaf(hn, fdv[i], d1);
            d2 = fmaf(hn, fav[i], d2);
        }
    }
#pragma unroll
    for (int m = 1; m <= 8; m <<= 1) {
        d1 += __shfl_xor(d1, m);
        d2 += __shfl_xor(d2, m);
    }
    if (csub == 0) {
        float r0 = fmaxf(d1, 0.f);
        float theta = d2 / (1.f + fabsf(d2)) * 0.017453292519943295f;
        int pos = p0 + gpos;
        OX[pos] = r0 * cosf(theta);
        OY[pos] = r0 * sinf(theta);
    }
}

// ---------------- K3: implicit GEMM deformable conv, full-N blocks, grid 256 ---------
// 256 blocks x 512 threads (8 waves), 1 block/CU. Block = full row (64 pos) x N=256.
// Wave = 64 pos (4 mf) x 32 outs (2 nf): B reuse 1:4, each a-frag feeds 2 MFMAs,
// A gathered ONCE per row (L2 A-traffic and lerp VALU halved vs N-half scheme).
// LDS: 4 x 16KB (tap-dbuf x K-half), R12's verified conflict-free 16-slot layout.
__launch_bounds__(512, 2)
__global__ void k_main(const unsigned short* __restrict__ xT,
                       const float* __restrict__ OX, const float* __restrict__ OY,
                       const unsigned short* __restrict__ Bt,
                       const float* __restrict__ bias,
                       float* __restrict__ out)
{
    __shared__ __align__(16) unsigned char smem[65536];   // [tap][half] 4 x 16KB

    int tid = threadIdx.x;
    int bi = blockIdx.x;
    int tile = ((bi & 7) << 5) | (bi >> 3);  // XCD-chunked over 256 rows
    int b = tile >> 6;
    int y = tile & 63;

    int lane = tid & 63, wid = tid >> 6;     // wid 0..7 -> outs wid*32..+31
    int l15 = lane & 15, l4 = lane >> 4;

    f32x4 acc[4][2];
#pragma unroll
    for (int m = 0; m < 4; ++m)
#pragma unroll
        for (int n = 0; n < 2; ++n) {
            acc[m][n].x = 0.f; acc[m][n].y = 0.f; acc[m][n].z = 0.f; acc[m][n].w = 0.f;
        }

    int gpos = tid >> 3;                   // 0..63 : position (x coordinate)
    unsigned csub = (unsigned)tid & 7u;
    const char* xbB = (const char*)(xT + (size_t)b * HW_ * C_);
    const unsigned short* bwave = Bt + (unsigned)(wid * 2) * 4096u
                                     + (unsigned)(l15 * 32 + l4 * 8);
    unsigned rowb = (unsigned)gpos * 256u;                        // 256B per half-row
    unsigned wsl0 = (csub ^ ((unsigned)gpos & 15u)) << 4;
    unsigned wsl1 = ((8u + csub) ^ ((unsigned)gpos & 15u)) << 4;
    float ox = OX[(tile << 6) + gpos], oy = OY[(tile << 6) + gpos];

    // persistent per-tap gather state
    unsigned o00, o01, o10, o11;
    f32x2 W00, W01, W10, W11;

#define GADDR(k)                                                                  \
    {   int ky = (k) / 3, kx = (k) - ky * 3;                                      \
        float dyv = ((k) <= 4) ? ox : oy;                                         \
        float dxv = ((k) <= 3) ? ox : oy;                                         \
        float py = (float)(y - 1 + ky) + dyv;                                     \
        float px = (float)(gpos - 1 + kx) + dxv;                                  \
        float y0f = floorf(py), x0f = floorf(px);                                 \
        int y0 = (int)y0f, x0 = (int)x0f;                                         \
        int y1 = y0 + 1, x1 = x0 + 1;                                             \
        float wy1 = py - y0f, wy0 = 1.f - wy1;                                    \
        float wx1 = px - x0f, wx0 = 1.f - wx1;                                    \
        float vy0 = (y0 >= 0 && y0 < H_) ? 1.f : 0.f;                             \
        float vy1 = (y1 >= 0 && y1 < H_) ? 1.f : 0.f;                             \
        float vx0 = (x0 >= 0 && x0 < W_) ? 1.f : 0.f;                             \
        float vx1 = (x1 >= 0 && x1 < W_) ? 1.f : 0.f;                             \
        float w00 = wy0 * wx0 * vy0 * vx0, w01 = wy0 * wx1 * vy0 * vx1;           \
        float w10 = wy1 * wx0 * vy1 * vx0, w11 = wy1 * wx1 * vy1 * vx1;           \
        W00.x = w00; W00.y = w00; W01.x = w01; W01.y = w01;                       \
        W10.x = w10; W10.y = w10; W11.x = w11; W11.y = w11;                       \
        int y0c = min(max(y0, 0), H_ - 1), y1c = min(max(y1, 0), H_ - 1);         \
        int x0c = min(max(x0, 0), W_ - 1), x1c = min(max(x1, 0), W_ - 1);         \
        unsigned cb = csub << 4;                                                  \
        o00 = (unsigned)((y0c << 6) + x0c) * 512u + cb;                           \
        o01 = (unsigned)((y0c << 6) + x1c) * 512u + cb;                           \
        o10 = (unsigned)((y1c << 6) + x0c) * 512u + cb;                           \
        o11 = (unsigned)((y1c << 6) + x1c) * 512u + cb;                           \
    }

    // gather channels [h*128,(h+1)*128) of this position into 16KB buffer at hbase
#define GATHER_HALF(h, hbase)                                                     \
    {   _Pragma("unroll")                                                         \
        for (int cq2 = 0; cq2 < 2; ++cq2) {                                       \
            unsigned gb = (unsigned)(h) * 256u + (unsigned)cq2 * 128u;            \
            short8 r00 = *(const short8*)(xbB + o00 + gb);                        \
            short8 r01 = *(const short8*)(xbB + o01 + gb);                        \
            short8 r10 = *(const short8*)(xbB + o10 + gb);                        \
            short8 r11 = *(const short8*)(xbB + o11 + gb);                        \
            uint4 pkv;                                                            \
            _Pragma("unroll")                                                     \
            for (int dw = 0; dw < 4; ++dw) {                                      \
                f32x2 a2 = pk_mul(unpack_bf2(((unsigned*)&r00)[dw]), W00);        \
                a2 = pk_fma(unpack_bf2(((unsigned*)&r01)[dw]), W01, a2);          \
                a2 = pk_fma(unpack_bf2(((unsigned*)&r10)[dw]), W10, a2);          \
                a2 = pk_fma(unpack_bf2(((unsigned*)&r11)[dw]), W11, a2);          \
                ((unsigned*)&pkv)[dw] = cvtpk(a2.x, a2.y);                        \
            }                                                                     \
            *(uint4*)(smem + (hbase) + rowb + (cq2 ? wsl1 : wsl0)) = pkv;         \
        }                                                                         \
    }

    // MFMA on K-half h of tap k from buffer hbase: 4 ks2 x (2 B loads + 4 a + 8 MFMA)
#define MFMA_HALF(k, h, hbase)                                                    \
    {   const unsigned short* bk = bwave + (unsigned)(k) * 65536u;                \
        _Pragma("unroll")                                                         \
        for (int ks2 = 0; ks2 < 4; ++ks2) {                                       \
            int ks = (h) * 4 + ks2;                                               \
            short8 bf0 = *(const short8*)(bk + ks * 512);                         \
            short8 bf1 = *(const short8*)(bk + 4096 + ks * 512);                  \
            unsigned sl = ((unsigned)(ks2 * 4 + l4) ^ (unsigned)l15) << 4;        \
            _Pragma("unroll")                                                     \
            for (int mf = 0; mf < 4; ++mf) {                                      \
                unsigned row = (unsigned)(mf * 16 + l15);                         \
                short8 a = *(const short8*)(smem + (hbase) + row * 256u + sl);    \
                acc[mf][0] = __builtin_amdgcn_mfma_f32_16x16x32_bf16(a, bf0, acc[mf][0], 0, 0, 0); \
                acc[mf][1] = __builtin_amdgcn_mfma_f32_16x16x32_bf16(a, bf1, acc[mf][1], 0, 0, 0); \
            }                                                                     \
        }                                                                         \
    }

    // ---- prologue: tap 0 (both halves) into buffers t=0 ----
    GADDR(0);
    GATHER_HALF(0, 0u);
    GATHER_HALF(1, 16384u);
    __syncthreads();

#pragma unroll
    for (int k = 0; k < 9; ++k) {
        unsigned cur = (k & 1) ? 32768u : 0u;
        unsigned nxt = (k & 1) ? 0u : 32768u;
        // issue next tap's gather (loads fly while MFMA below runs)
        if (k < 8) {
            GADDR(k + 1);
            GATHER_HALF(0, nxt);
            GATHER_HALF(1, nxt + 16384u);
        }
        MFMA_HALF(k, 0, cur);
        MFMA_HALF(k, 1, cur + 16384u);
        __syncthreads();
    }

    // ---- epilogue: direct global stores ----
#pragma unroll
    for (int nf = 0; nf < 2; ++nf) {
        int col = wid * 32 + nf * 16 + l15;
        float bv = bias[col];
        float* obase = out + ((size_t)(b * CO_ + col)) * HW_ + (y << 6);
#pragma unroll
        for (int mf = 0; mf < 4; ++mf) {
            f32x4 v;
            v.x = acc[mf][nf].x + bv;
            v.y = acc[mf][nf].y + bv;
            v.z = acc[mf][nf].z + bv;
            v.w = acc[mf][nf].w + bv;
            *(f32x4*)(obase + mf * 16 + l4 * 4) = v;
        }
    }
}

extern "C" void kernel_launch(void* const* d_in, const int* in_sizes, int n_in,
                              void* d_out, int out_size, void* d_ws, size_t ws_size,
                              hipStream_t stream) {
    const float* x      = (const float*)d_in[0];
    const float* dwc_w  = (const float*)d_in[1];
    const float* ln_w   = (const float*)d_in[2];
    const float* ln_b   = (const float*)d_in[3];
    const float* fcd_w  = (const float*)d_in[4];
    const float* fca_w  = (const float*)d_in[5];
    const float* dconv_w= (const float*)d_in[6];
    const float* dconv_b= (const float*)d_in[7];
    float* out = (float*)d_out;

    unsigned char* ws = (unsigned char*)d_ws;
    unsigned short* xT = (unsigned short*)(ws);                 // 8 MB bf16 NHWC
    unsigned short* Bt = (unsigned short*)(ws + 8388608);       // 1.18 MB
    float* dwcT        = (float*)(ws + 9568256);                // 9 KB
    float* OX          = (float*)(ws + 9577472);                // 64 KB
    float* OY          = (float*)(ws + 9643008);                // 64 KB

    k_pre<<<3328, 256, 0, stream>>>(x, xT, dconv_w, Bt, dwc_w, dwcT);
    k_offsets<<<512, 512, 0, stream>>>(xT, dwcT, ln_w, ln_b, fcd_w, fca_w, OX, OY);
    k_main<<<256, 512, 0, stream>>>(xT, OX, OY, Bt, dconv_b, out);
}